// Round 5
// baseline (49.190 us; speedup 1.0000x reference)
//
#include <hip/hip_runtime.h>
#include <cmath>
#include <complex>

// ChebyUpsample: x (256, 32768) f32 -> repeat x2 -> reverse -> cheby1(8,0.05,0.5)
// 4-biquad cascade -> reverse -> y (256, 65536) f32.
// Reversed-time chunked IIR, fully LDS-staged:
//   block = 256 threads = 256 chunks of 32 inputs (64 outputs), tile = 8192+64.
//   Warm-up 128 steps from staged halo (zeros past signal end = exact).
//   Single 33KB LDS buffer: input tile during compute, then ALIASED as the
//   output transpose buffer (4 blocks/CU). Flush is per-wave, barrier-free:
//   each wave transposes its own 64 chunks through its private quarter in 2
//   rounds (same-wave DS ordering via lgkmcnt), stores as 128B full-line runs.
// Swizzle SWZ(q)=q^(((q>>6)&7)<<2): 16B-granular, bijective, keeps b128
// accesses at the conflict-free 8-accesses-per-bank-group floor.

struct SosC {
  float g;       // kz gain folded into staged input
  float a1[4];
  float a2[4];
};

struct G2 { float4 a, b; };   // a = s[qq..qq+3], b = s[qq+4..qq+7]

#define SWZ(q) ((q) ^ ((((q) >> 6) & 7) << 2))

__global__ __launch_bounds__(256, 4)
void cheby_up_kernel(const float* __restrict__ x, float* __restrict__ y, SosC c) {
  constexpr int T_IN = 32768;
  __shared__ __align__(16) float lbuf[8256];   // tile+halo, later output xpose

  const int row = blockIdx.y;
  const int b   = blockIdx.x;          // tile 0..3 within row
  const int t   = threadIdx.x;         // local chunk id 0..255
  const float* xrow = x + (size_t)row * T_IN;
  float*       yrow = y + (size_t)row * (size_t)(2 * T_IN);
  const int tbase = b * 8192;

  const float g = c.g;

  // ---- stage input tile, coalesced, pre-scaled by g ----
  #pragma unroll
  for (int j = 0; j < 8; ++j) {
    int q = 4 * t + 1024 * j;                       // 0..8191
    float4 v = *reinterpret_cast<const float4*>(xrow + tbase + q);
    v.x *= g; v.y *= g; v.z *= g; v.w *= g;
    *reinterpret_cast<float4*>(&lbuf[SWZ(q)]) = v;
  }
  if (t < 16) {                                     // 64-float halo
    int q = 8192 + 4 * t;                           // SWZ is identity here
    int gi = tbase + q;
    float4 v = make_float4(0.f, 0.f, 0.f, 0.f);
    if (gi < T_IN) {
      v = *reinterpret_cast<const float4*>(xrow + gi);
      v.x *= g; v.y *= g; v.z *= g; v.w *= g;
    }
    *reinterpret_cast<float4*>(&lbuf[q]) = v;
  }
  __syncthreads();

  const float a10 = c.a1[0], a20 = c.a2[0];
  const float a11 = c.a1[1], a21 = c.a2[1];
  const float a12 = c.a1[2], a22 = c.a2[2];
  const float a13 = c.a1[3], a23 = c.a2[3];

  // transposed direct-form II states, 4 sections
  float z10=0.f, z20=0.f, z11=0.f, z21=0.f;
  float z12=0.f, z22=0.f, z13=0.f, z23=0.f;

  auto step = [&](float x0) -> float {
    float y0 = x0 + z10;
    z10 = fmaf(-a10, y0, fmaf(2.f, x0, z20));
    z20 = fmaf(-a20, y0, x0);
    float y1 = y0 + z11;
    z11 = fmaf(-a11, y1, fmaf(2.f, y0, z21));
    z21 = fmaf(-a21, y1, y0);
    float y2 = y1 + z12;
    z12 = fmaf(-a12, y2, fmaf(2.f, y1, z22));
    z22 = fmaf(-a22, y2, y1);
    float y3 = y2 + z13;
    z13 = fmaf(-a13, y3, fmaf(2.f, y2, z23));
    z23 = fmaf(-a23, y3, y2);
    return y3;
  };

  auto rd8 = [&](int qq) -> G2 {     // 8 consecutive staged samples
    G2 r;
    r.a = *reinterpret_cast<const float4*>(&lbuf[SWZ(qq)]);
    r.b = *reinterpret_cast<const float4*>(&lbuf[SWZ(qq + 4)]);
    return r;
  };

  // 16 filter steps over 8 inputs, reversed-time order = forward descending
  auto steps16 = [&](const G2& v) {
    float s;
    s = v.b.w; step(s); step(s);
    s = v.b.z; step(s); step(s);
    s = v.b.y; step(s); step(s);
    s = v.b.x; step(s); step(s);
    s = v.a.w; step(s); step(s);
    s = v.a.z; step(s); step(s);
    s = v.a.y; step(s); step(s);
    s = v.a.x; step(s); step(s);
  };

  float o[64];   // chunk outputs, local forward offsets 0..63 (static idx only)

  // ---- warm-up: 8 groups (64 inputs = 128 steps), chunk offsets [32,96) ----
  G2 cur = rd8(32 * t + 88);
  #pragma unroll
  for (int wg = 7; wg >= 1; --wg) {
    G2 nxt = rd8(32 * t + 32 + 8 * (wg - 1));
    steps16(cur);
    cur = nxt;
  }
  {
    G2 nxt = rd8(32 * t + 24);      // prefetch main mg=3
    steps16(cur);
    cur = nxt;
  }

  // ---- main: 4 groups x 8 inputs -> 16 outputs each (forward descending) ----
  #pragma unroll
  for (int mg = 3; mg >= 0; --mg) {
    G2 nxt = cur;
    if (mg > 0) nxt = rd8(32 * t + 8 * (mg - 1));
    float s;
    s = cur.b.w; o[16*mg+15] = step(s); o[16*mg+14] = step(s);
    s = cur.b.z; o[16*mg+13] = step(s); o[16*mg+12] = step(s);
    s = cur.b.y; o[16*mg+11] = step(s); o[16*mg+10] = step(s);
    s = cur.b.x; o[16*mg+9]  = step(s); o[16*mg+8]  = step(s);
    s = cur.a.w; o[16*mg+7]  = step(s); o[16*mg+6]  = step(s);
    s = cur.a.z; o[16*mg+5]  = step(s); o[16*mg+4]  = step(s);
    s = cur.a.y; o[16*mg+3]  = step(s); o[16*mg+2]  = step(s);
    s = cur.a.x; o[16*mg+1]  = step(s); o[16*mg+0]  = step(s);
    cur = nxt;
  }

  // ---- flush: per-wave transpose through this wave's 2048-float quarter ----
  // All compute must be done before lbuf is overwritten (neighbors read my
  // region during warm-up): one barrier, then barrier-free per-wave rounds.
  __syncthreads();
  const int w = t >> 6;              // wave id 0..3
  const int l = t & 63;              // lane
  #pragma unroll
  for (int r = 0; r < 2; ++r) {
    // write 32 of my outputs: lidx = 2048w + 32l + m, m in [0,32)
    #pragma unroll
    for (int i = 0; i < 8; ++i) {
      int q = 2048 * w + 32 * l + 4 * i;
      *reinterpret_cast<float4*>(&lbuf[SWZ(q)]) =
          make_float4(o[32*r+4*i], o[32*r+4*i+1], o[32*r+4*i+2], o[32*r+4*i+3]);
    }
    // read back lane-contiguous (same wave's data; lgkmcnt orders DS ops)
    #pragma unroll
    for (int j = 0; j < 8; ++j) {
      int local = 4 * l + 256 * j;           // 0..2047
      float4 v = *reinterpret_cast<const float4*>(&lbuf[SWZ(2048 * w + local)]);
      int c64 = local >> 5;                  // source chunk lane 0..63
      int m   = local & 31;                  // output offset within round
      // chunk (64w + c64), outputs [32r, 32r+32): 128B-aligned full-line runs
      *reinterpret_cast<float4*>(yrow + 16384 * b + 64 * (64 * w + c64) + 32 * r + m) = v;
    }
  }
}

// Host-side replication of _cheby1_sos(8, 0.05, 0.5) in double precision.
static SosC compute_coefs() {
  const int N = 8;
  const double rp = 0.05, Wn = 0.5;
  const double PI = 3.14159265358979323846;
  double eps = std::sqrt(std::pow(10.0, 0.1 * rp) - 1.0);
  double mu = std::asinh(1.0 / eps) / (double)N;
  std::complex<double> p[8];
  std::complex<double> prodNegP(1.0, 0.0);
  int idx = 0;
  for (int m = -N + 1; m < N; m += 2) {
    double theta = PI * (double)m / (2.0 * N);
    std::complex<double> pp = -std::sinh(std::complex<double>(mu, theta));
    p[idx++] = pp;
    prodNegP *= -pp;
  }
  double k = prodNegP.real();
  k /= std::sqrt(1.0 + eps * eps);          // even N
  const double fs = 2.0;
  double warped = 2.0 * fs * std::tan(PI * Wn / fs);
  for (int i = 0; i < 8; i++) p[i] *= warped;
  k *= std::pow(warped, (double)N);
  const double fs2 = 2.0 * fs;
  std::complex<double> prodDen(1.0, 0.0);
  for (int i = 0; i < 8; i++) prodDen *= (fs2 - p[i]);
  double kz = k * (1.0 / prodDen).real();

  SosC c;
  int s = 0;
  for (int i = 0; i < 8; i++) {
    std::complex<double> pz = (fs2 + p[i]) / (fs2 - p[i]);
    if (pz.imag() > 0.0) {                  // same selection order as numpy
      c.a1[s] = (float)(-2.0 * pz.real());
      c.a2[s] = (float)std::norm(pz);       // |pz|^2
      s++;
    }
  }
  c.g = (float)kz;
  return c;
}

extern "C" void kernel_launch(void* const* d_in, const int* in_sizes, int n_in,
                              void* d_out, int out_size, void* d_ws, size_t ws_size,
                              hipStream_t stream) {
  const float* x = (const float*)d_in[0];
  float* y = (float*)d_out;
  SosC c = compute_coefs();
  int rows = in_sizes[0] / 32768;   // 256
  dim3 grid(4, rows);               // 4 tiles/row, 256 chunks per tile
  cheby_up_kernel<<<grid, 256, 0, stream>>>(x, y, c);
}

// Round 6
// 31.001 us; speedup vs baseline: 1.5867x; 1.5867x over previous
//
#include <hip/hip_runtime.h>
#include <cmath>
#include <complex>

// ChebyUpsample: x (256, 32768) f32 -> repeat x2 -> reverse -> cheby1(8,0.05,0.5)
// 4-biquad cascade -> reverse -> y (256, 65536) f32.
// Reversed-time chunked IIR, fully LDS-staged:
//   block = 256 threads = 256 chunks of 32 inputs (64 outputs), tile = 8192+64.
//   Warm-up 128 steps from staged halo (zeros past signal end = exact; W=128
//   is accuracy-mandatory: absmax ~ rho^W, W=96 would fail the 0.1 threshold).
//   After warm-up each thread copies its own 32 inputs to registers -> lbuf is
//   dead -> ONE barrier -> two phases of {compute 32 outputs, per-wave flush
//   through the wave's private LDS quarter (barrier-free, same-wave lgkmcnt
//   ordering)}. Peak ~90 VGPR: no spill (round-5 lesson: VGPR=64 cap spilled
//   o[64] -> +64MB scratch writes). 33KB LDS -> 4 blocks/CU.
// Swizzle SWZ(q)=q^(((q>>6)&7)<<2): 16B-granular, bijective, keeps b128
// accesses at the 8-cycle data floor for stride-32 patterns.

struct SosC {
  float g;       // kz gain folded into staged input
  float a1[4];
  float a2[4];
};

struct G2 { float4 a, b; };   // a = s[qq..qq+3], b = s[qq+4..qq+7]

#define SWZ(q) ((q) ^ ((((q) >> 6) & 7) << 2))

__global__ __launch_bounds__(256)
void cheby_up_kernel(const float* __restrict__ x, float* __restrict__ y, SosC c) {
  constexpr int T_IN = 32768;
  __shared__ __align__(16) float lbuf[8256];   // tile+halo, later output xpose

  const int row = blockIdx.y;
  const int b   = blockIdx.x;          // tile 0..3 within row
  const int t   = threadIdx.x;         // local chunk id 0..255
  const float* xrow = x + (size_t)row * T_IN;
  float*       yrow = y + (size_t)row * (size_t)(2 * T_IN);
  const int tbase = b * 8192;

  const float g = c.g;

  // ---- stage input tile, coalesced, pre-scaled by g ----
  #pragma unroll
  for (int j = 0; j < 8; ++j) {
    int q = 4 * t + 1024 * j;                       // 0..8191
    float4 v = *reinterpret_cast<const float4*>(xrow + tbase + q);
    v.x *= g; v.y *= g; v.z *= g; v.w *= g;
    *reinterpret_cast<float4*>(&lbuf[SWZ(q)]) = v;
  }
  if (t < 16) {                                     // 64-float halo
    int q = 8192 + 4 * t;                           // SWZ is identity here
    int gi = tbase + q;
    float4 v = make_float4(0.f, 0.f, 0.f, 0.f);
    if (gi < T_IN) {
      v = *reinterpret_cast<const float4*>(xrow + gi);
      v.x *= g; v.y *= g; v.z *= g; v.w *= g;
    }
    *reinterpret_cast<float4*>(&lbuf[q]) = v;
  }
  __syncthreads();

  const float a10 = c.a1[0], a20 = c.a2[0];
  const float a11 = c.a1[1], a21 = c.a2[1];
  const float a12 = c.a1[2], a22 = c.a2[2];
  const float a13 = c.a1[3], a23 = c.a2[3];

  // transposed direct-form II states, 4 sections
  float z10=0.f, z20=0.f, z11=0.f, z21=0.f;
  float z12=0.f, z22=0.f, z13=0.f, z23=0.f;

  auto step = [&](float x0) -> float {
    float y0 = x0 + z10;
    z10 = fmaf(-a10, y0, fmaf(2.f, x0, z20));
    z20 = fmaf(-a20, y0, x0);
    float y1 = y0 + z11;
    z11 = fmaf(-a11, y1, fmaf(2.f, y0, z21));
    z21 = fmaf(-a21, y1, y0);
    float y2 = y1 + z12;
    z12 = fmaf(-a12, y2, fmaf(2.f, y1, z22));
    z22 = fmaf(-a22, y2, y1);
    float y3 = y2 + z13;
    z13 = fmaf(-a13, y3, fmaf(2.f, y2, z23));
    z23 = fmaf(-a23, y3, y2);
    return y3;
  };

  auto rd8 = [&](int qq) -> G2 {     // 8 consecutive staged samples
    G2 r;
    r.a = *reinterpret_cast<const float4*>(&lbuf[SWZ(qq)]);
    r.b = *reinterpret_cast<const float4*>(&lbuf[SWZ(qq + 4)]);
    return r;
  };

  // 16 filter steps over 8 inputs, reversed-time order = forward descending
  auto steps16 = [&](const G2& v) {
    float s;
    s = v.b.w; step(s); step(s);
    s = v.b.z; step(s); step(s);
    s = v.b.y; step(s); step(s);
    s = v.b.x; step(s); step(s);
    s = v.a.w; step(s); step(s);
    s = v.a.z; step(s); step(s);
    s = v.a.y; step(s); step(s);
    s = v.a.x; step(s); step(s);
  };

  // ---- warm-up: 8 groups (64 inputs = 128 steps), chunk offsets [32,96) ----
  G2 cur = rd8(32 * t + 88);
  #pragma unroll
  for (int wg = 7; wg >= 1; --wg) {
    G2 nxt = rd8(32 * t + 32 + 8 * (wg - 1));
    steps16(cur);
    cur = nxt;
  }

  // own 32 inputs -> registers; lbuf input region becomes dead after this
  G2 g3 = rd8(32 * t + 24);   // floats [24,32)
  G2 g2 = rd8(32 * t + 16);   // [16,24)
  G2 g1 = rd8(32 * t + 8);    // [8,16)
  G2 g0 = rd8(32 * t);        // [0,8)
  steps16(cur);               // last warm group (offset 32)
  __syncthreads();            // ALL lbuf reads complete; safe to alias

  const int w = t >> 6;       // wave id 0..3
  const int l = t & 63;       // lane
  const int Q = 2048 * w;     // this wave's private LDS quarter

  float o[32];                // static indices only (fully unrolled)

  // per-wave barrier-free transpose+store of 32 outputs at chunk offset `half`
  auto flush32 = [&](int half) {
    #pragma unroll
    for (int i = 0; i < 8; ++i) {
      int q = Q + 32 * l + 4 * i;
      *reinterpret_cast<float4*>(&lbuf[SWZ(q)]) =
          make_float4(o[4*i], o[4*i+1], o[4*i+2], o[4*i+3]);
    }
    float* yG = yrow + 16384 * b + 4096 * w + half;
    #pragma unroll
    for (int j = 0; j < 8; ++j) {
      int local = 4 * l + 256 * j;                     // 0..2047
      float4 v = *reinterpret_cast<const float4*>(&lbuf[SWZ(Q + local)]);
      int c64 = local >> 5;                            // chunk lane 0..63
      int m   = local & 31;                            // offset within half
      *reinterpret_cast<float4*>(yG + 64 * c64 + m) = v;   // 128B-aligned runs
    }
  };

  // ---- phase A: outputs [32,64) from inputs [16,32) (forward descending) ----
  {
    float s;
    s = g3.b.w; o[31] = step(s); o[30] = step(s);
    s = g3.b.z; o[29] = step(s); o[28] = step(s);
    s = g3.b.y; o[27] = step(s); o[26] = step(s);
    s = g3.b.x; o[25] = step(s); o[24] = step(s);
    s = g3.a.w; o[23] = step(s); o[22] = step(s);
    s = g3.a.z; o[21] = step(s); o[20] = step(s);
    s = g3.a.y; o[19] = step(s); o[18] = step(s);
    s = g3.a.x; o[17] = step(s); o[16] = step(s);
    s = g2.b.w; o[15] = step(s); o[14] = step(s);
    s = g2.b.z; o[13] = step(s); o[12] = step(s);
    s = g2.b.y; o[11] = step(s); o[10] = step(s);
    s = g2.b.x; o[9]  = step(s); o[8]  = step(s);
    s = g2.a.w; o[7]  = step(s); o[6]  = step(s);
    s = g2.a.z; o[5]  = step(s); o[4]  = step(s);
    s = g2.a.y; o[3]  = step(s); o[2]  = step(s);
    s = g2.a.x; o[1]  = step(s); o[0]  = step(s);
  }
  flush32(32);

  // ---- phase B: outputs [0,32) from inputs [0,16) ----
  {
    float s;
    s = g1.b.w; o[31] = step(s); o[30] = step(s);
    s = g1.b.z; o[29] = step(s); o[28] = step(s);
    s = g1.b.y; o[27] = step(s); o[26] = step(s);
    s = g1.b.x; o[25] = step(s); o[24] = step(s);
    s = g1.a.w; o[23] = step(s); o[22] = step(s);
    s = g1.a.z; o[21] = step(s); o[20] = step(s);
    s = g1.a.y; o[19] = step(s); o[18] = step(s);
    s = g1.a.x; o[17] = step(s); o[16] = step(s);
    s = g0.b.w; o[15] = step(s); o[14] = step(s);
    s = g0.b.z; o[13] = step(s); o[12] = step(s);
    s = g0.b.y; o[11] = step(s); o[10] = step(s);
    s = g0.b.x; o[9]  = step(s); o[8]  = step(s);
    s = g0.a.w; o[7]  = step(s); o[6]  = step(s);
    s = g0.a.z; o[5]  = step(s); o[4]  = step(s);
    s = g0.a.y; o[3]  = step(s); o[2]  = step(s);
    s = g0.a.x; o[1]  = step(s); o[0]  = step(s);
  }
  flush32(0);
}

// Host-side replication of _cheby1_sos(8, 0.05, 0.5) in double precision.
static SosC compute_coefs() {
  const int N = 8;
  const double rp = 0.05, Wn = 0.5;
  const double PI = 3.14159265358979323846;
  double eps = std::sqrt(std::pow(10.0, 0.1 * rp) - 1.0);
  double mu = std::asinh(1.0 / eps) / (double)N;
  std::complex<double> p[8];
  std::complex<double> prodNegP(1.0, 0.0);
  int idx = 0;
  for (int m = -N + 1; m < N; m += 2) {
    double theta = PI * (double)m / (2.0 * N);
    std::complex<double> pp = -std::sinh(std::complex<double>(mu, theta));
    p[idx++] = pp;
    prodNegP *= -pp;
  }
  double k = prodNegP.real();
  k /= std::sqrt(1.0 + eps * eps);          // even N
  const double fs = 2.0;
  double warped = 2.0 * fs * std::tan(PI * Wn / fs);
  for (int i = 0; i < 8; i++) p[i] *= warped;
  k *= std::pow(warped, (double)N);
  const double fs2 = 2.0 * fs;
  std::complex<double> prodDen(1.0, 0.0);
  for (int i = 0; i < 8; i++) prodDen *= (fs2 - p[i]);
  double kz = k * (1.0 / prodDen).real();

  SosC c;
  int s = 0;
  for (int i = 0; i < 8; i++) {
    std::complex<double> pz = (fs2 + p[i]) / (fs2 - p[i]);
    if (pz.imag() > 0.0) {                  // same selection order as numpy
      c.a1[s] = (float)(-2.0 * pz.real());
      c.a2[s] = (float)std::norm(pz);       // |pz|^2
      s++;
    }
  }
  c.g = (float)kz;
  return c;
}

extern "C" void kernel_launch(void* const* d_in, const int* in_sizes, int n_in,
                              void* d_out, int out_size, void* d_ws, size_t ws_size,
                              hipStream_t stream) {
  const float* x = (const float*)d_in[0];
  float* y = (float*)d_out;
  SosC c = compute_coefs();
  int rows = in_sizes[0] / 32768;   // 256
  dim3 grid(4, rows);               // 4 tiles/row, 256 chunks per tile
  cheby_up_kernel<<<grid, 256, 0, stream>>>(x, y, c);
}